// Round 3
// baseline (929.614 us; speedup 1.0000x reference)
//
#include <hip/hip_runtime.h>

// EncoderBlock: x:[2,2048,1024] FP32 in/out (per reference dtypes).
// Internal compute: fp16 MFMA (16x16x32_f16), fp32 softmax/LN/residual chain.
// B=2 S=2048 D=1024 H=16 DH=64 FF=4096, T=4096 tokens.
// ws: h[8MB fp16] | Q[8MB] | K[8MB] | V[8MB]; x1 fp32 (16MB) overlays dead K+V;
// FFN intermediate quarters reuse Q region. Peak 32MB.

typedef _Float16 half8 __attribute__((ext_vector_type(8)));
typedef _Float16 half4 __attribute__((ext_vector_type(4)));
typedef float floatx4 __attribute__((ext_vector_type(4)));

// ---------------- LayerNorm fp32 -> fp16 (ddof=1, g*(x-mean)/(std+eps)+b) ----
__global__ __launch_bounds__(256) void ln_kernel(const float* __restrict__ x,
                                                 const float* __restrict__ g,
                                                 const float* __restrict__ be,
                                                 _Float16* __restrict__ out) {
    int row = blockIdx.x;
    int tid = threadIdx.x;
    floatx4 v = ((const floatx4*)(x + (size_t)row * 1024))[tid];
    float s = 0.f, ss = 0.f;
#pragma unroll
    for (int i = 0; i < 4; i++) { s += v[i]; ss += v[i] * v[i]; }
#pragma unroll
    for (int off = 1; off < 64; off <<= 1) {
        s += __shfl_xor(s, off);
        ss += __shfl_xor(ss, off);
    }
    __shared__ float sm[8];
    int wave = tid >> 6, lane = tid & 63;
    if (lane == 0) { sm[wave] = s; sm[wave + 4] = ss; }
    __syncthreads();
    s = sm[0] + sm[1] + sm[2] + sm[3];
    ss = sm[4] + sm[5] + sm[6] + sm[7];
    float mean = s * (1.f / 1024.f);
    float var = (ss - s * mean) * (1.f / 1023.f);        // Bessel ddof=1
    float rs = 1.f / (sqrtf(fmaxf(var, 0.f)) + 1e-6f);   // std + eps
    floatx4 gv = ((const floatx4*)g)[tid];
    floatx4 bv = ((const floatx4*)be)[tid];
    half4 o;
#pragma unroll
    for (int i = 0; i < 4; i++) o[i] = (_Float16)(gv[i] * (v[i] - mean) * rs + bv[i]);
    ((half4*)(out + (size_t)row * 1024))[tid] = o;
}

// ---------------- MFMA GEMM: C = [relu](A@B + bias) + res ----------------
// A: fp16 ws, row-major, stride Kdim. B: fp32 global weights [*, Bstride].
// res: fp32 stride N (may alias Cout -> no restrict). Cout fp16 or fp32.
// 64x64 tile, 4 waves of 32x32, mfma_f32_16x16x32_f16.
__global__ __launch_bounds__(256) void gemm_kernel(const _Float16* __restrict__ A,
                                                   const float* __restrict__ B,
                                                   const float* __restrict__ bias,
                                                   const float* res, void* Cout,
                                                   int N, int Kdim, int Bstride,
                                                   int relu_flag, int out_fp16) {
    __shared__ _Float16 As[64][72];   // +8 pad: 16B-aligned rows, 2-way bank alias only
    __shared__ _Float16 Bs[64][72];   // transposed: Bs[n][k]
    int bn = blockIdx.x * 64, bm = blockIdx.y * 64;
    int tid = threadIdx.x;
    int wave = tid >> 6, lane = tid & 63, quad = lane >> 4, l15 = lane & 15;
    int wm = (wave & 1) * 32, wn = (wave >> 1) * 32;

    floatx4 zero = {0.f, 0.f, 0.f, 0.f};
    floatx4 acc[2][2];
    acc[0][0] = zero; acc[0][1] = zero; acc[1][0] = zero; acc[1][1] = zero;

    for (int k0 = 0; k0 < Kdim; k0 += 64) {
        __syncthreads();
        // A tile: 64x64 fp16, 2 x half8 per thread
#pragma unroll
        for (int i = 0; i < 2; i++) {
            int v = tid + i * 256;
            int r = v >> 3, c = (v & 7) * 8;
            *(half8*)&As[r][c] = *(const half8*)(A + (size_t)(bm + r) * Kdim + k0 + c);
        }
        // B tile: 64x64 fp32 -> cvt fp16, transposed scatter. 4 x float4 per thread.
#pragma unroll
        for (int i = 0; i < 4; i++) {
            int v = tid + i * 256;
            int r = v >> 4, c = (v & 15) * 4;
            floatx4 bv = *(const floatx4*)(B + (size_t)(k0 + r) * Bstride + bn + c);
#pragma unroll
            for (int j = 0; j < 4; j++) Bs[c + j][r] = (_Float16)bv[j];
        }
        __syncthreads();
#pragma unroll
        for (int kk = 0; kk < 2; kk++) {
            half8 a0 = *(const half8*)&As[wm + l15][kk * 32 + quad * 8];
            half8 a1 = *(const half8*)&As[wm + 16 + l15][kk * 32 + quad * 8];
            half8 b0 = *(const half8*)&Bs[wn + l15][kk * 32 + quad * 8];
            half8 b1 = *(const half8*)&Bs[wn + 16 + l15][kk * 32 + quad * 8];
            acc[0][0] = __builtin_amdgcn_mfma_f32_16x16x32_f16(a0, b0, acc[0][0], 0, 0, 0);
            acc[0][1] = __builtin_amdgcn_mfma_f32_16x16x32_f16(a0, b1, acc[0][1], 0, 0, 0);
            acc[1][0] = __builtin_amdgcn_mfma_f32_16x16x32_f16(a1, b0, acc[1][0], 0, 0, 0);
            acc[1][1] = __builtin_amdgcn_mfma_f32_16x16x32_f16(a1, b1, acc[1][1], 0, 0, 0);
        }
    }
    // C/D layout: col = lane&15, row = quad*4 + reg  [m89/m91; dtype-independent m121]
#pragma unroll
    for (int im = 0; im < 2; im++)
#pragma unroll
        for (int in = 0; in < 2; in++)
#pragma unroll
            for (int r = 0; r < 4; r++) {
                int row = bm + wm + im * 16 + quad * 4 + r;
                int col = bn + wn + in * 16 + l15;
                float val = acc[im][in][r];
                if (bias) val += bias[col];
                if (relu_flag) val = fmaxf(val, 0.f);
                if (res) val += res[(size_t)row * N + col];
                if (out_fp16) ((_Float16*)Cout)[(size_t)row * N + col] = (_Float16)val;
                else          ((float*)Cout)[(size_t)row * N + col] = val;
            }
}

// ---------------- Flash attention, fp16 frags / fp32 softmax ----------------
// O may alias Q in-place: block (qt,h) is the only writer/reader of its Q tile,
// and Q is staged to LDS before any O store.
__global__ __launch_bounds__(256) void attn_kernel(const _Float16* Q,
                                                   const _Float16* __restrict__ K,
                                                   const _Float16* __restrict__ V,
                                                   _Float16* O) {
    const int LD = 1024;
    int qt = blockIdx.x;           // 0..31 q-tiles
    int bh = blockIdx.y;           // 0..31 (b*16+h)
    int b = bh >> 4, h = bh & 15;
    int col0 = h * 64;
    int tbase = b * 2048;

    __shared__ _Float16 Qs[64][72];
    __shared__ _Float16 Ks[64][72];
    __shared__ _Float16 Vt[64][72];   // Vt[dim][key]
    __shared__ _Float16 Ps[64][72];

    int tid = threadIdx.x;
    int wave = tid >> 6, lane = tid & 63, quad = lane >> 4, l15 = lane & 15;

#pragma unroll
    for (int i = 0; i < 2; i++) {
        int v = tid + i * 256;
        int r = v >> 3, c = (v & 7) * 8;
        *(half8*)&Qs[r][c] = *(const half8*)(Q + (size_t)(tbase + qt * 64 + r) * LD + col0 + c);
    }

    floatx4 zero = {0.f, 0.f, 0.f, 0.f};
    floatx4 o_acc[4];
#pragma unroll
    for (int jn = 0; jn < 4; jn++) o_acc[jn] = zero;
    float m_i[4] = {-1e30f, -1e30f, -1e30f, -1e30f};
    float l_i[4] = {0.f, 0.f, 0.f, 0.f};

    for (int kt = 0; kt < 32; kt++) {
        __syncthreads();   // prev iteration's Vt/Ps readers done
#pragma unroll
        for (int i = 0; i < 2; i++) {
            int v = tid + i * 256;
            int r = v >> 3, c = (v & 7) * 8;
            *(half8*)&Ks[r][c] = *(const half8*)(K + (size_t)(tbase + kt * 64 + r) * LD + col0 + c);
            half8 vv = *(const half8*)(V + (size_t)(tbase + kt * 64 + r) * LD + col0 + c);
#pragma unroll
            for (int j = 0; j < 8; j++) Vt[c + j][r] = vv[j];
        }
        __syncthreads();

        // S = Q@K^T: this wave's 16 q-rows x 64 keys
        floatx4 s_acc[4];
#pragma unroll
        for (int jn = 0; jn < 4; jn++) s_acc[jn] = zero;
#pragma unroll
        for (int kk = 0; kk < 2; kk++) {
            half8 a = *(const half8*)&Qs[16 * wave + l15][kk * 32 + quad * 8];
#pragma unroll
            for (int jn = 0; jn < 4; jn++) {
                half8 bb = *(const half8*)&Ks[16 * jn + l15][kk * 32 + quad * 8];
                s_acc[jn] = __builtin_amdgcn_mfma_f32_16x16x32_f16(a, bb, s_acc[jn], 0, 0, 0);
            }
        }

        // online softmax: lane owns rows quad*4+r, cols l15 + 16*jn
        float alpha[4];
#pragma unroll
        for (int r = 0; r < 4; r++) {
            float mx = -1e30f;
#pragma unroll
            for (int jn = 0; jn < 4; jn++) {
                s_acc[jn][r] *= 0.125f;   // 1/sqrt(64)
                mx = fmaxf(mx, s_acc[jn][r]);
            }
#pragma unroll
            for (int off = 1; off < 16; off <<= 1) mx = fmaxf(mx, __shfl_xor(mx, off));
            float mnew = fmaxf(m_i[r], mx);
            float d = m_i[r] - mnew;
            alpha[r] = (d < -60.f) ? 0.f : __expf(d);
            m_i[r] = mnew;
        }
#pragma unroll
        for (int r = 0; r < 4; r++) {
            float sum = 0.f;
#pragma unroll
            for (int jn = 0; jn < 4; jn++) {
                float d = s_acc[jn][r] - m_i[r];
                float p = (d < -60.f) ? 0.f : __expf(d);
                s_acc[jn][r] = p;
                sum += p;
            }
#pragma unroll
            for (int off = 1; off < 16; off <<= 1) sum += __shfl_xor(sum, off);
            l_i[r] = l_i[r] * alpha[r] + sum;
        }

        // P: C-layout -> LDS -> A-layout
#pragma unroll
        for (int jn = 0; jn < 4; jn++)
#pragma unroll
            for (int r = 0; r < 4; r++)
                Ps[16 * wave + quad * 4 + r][16 * jn + l15] = (_Float16)s_acc[jn][r];
        __syncthreads();

#pragma unroll
        for (int jn = 0; jn < 4; jn++)
#pragma unroll
            for (int r = 0; r < 4; r++) o_acc[jn][r] *= alpha[r];
#pragma unroll
        for (int kk = 0; kk < 2; kk++) {
            half8 a = *(const half8*)&Ps[16 * wave + l15][kk * 32 + quad * 8];
#pragma unroll
            for (int jn = 0; jn < 4; jn++) {
                half8 bb = *(const half8*)&Vt[16 * jn + l15][kk * 32 + quad * 8];
                o_acc[jn] = __builtin_amdgcn_mfma_f32_16x16x32_f16(a, bb, o_acc[jn], 0, 0, 0);
            }
        }
    }

#pragma unroll
    for (int jn = 0; jn < 4; jn++)
#pragma unroll
        for (int r = 0; r < 4; r++) {
            float val = o_acc[jn][r] / l_i[r];
            int row = tbase + qt * 64 + 16 * wave + quad * 4 + r;
            O[(size_t)row * LD + col0 + 16 * jn + l15] = (_Float16)val;
        }
}

extern "C" void kernel_launch(void* const* d_in, const int* in_sizes, int n_in,
                              void* d_out, int out_size, void* d_ws, size_t ws_size,
                              hipStream_t stream) {
    const float* x   = (const float*)d_in[0];
    const float* wq  = (const float*)d_in[1];
    const float* wk  = (const float*)d_in[2];
    const float* wv  = (const float*)d_in[3];
    const float* wo  = (const float*)d_in[4];
    const float* w1  = (const float*)d_in[5];
    const float* b1  = (const float*)d_in[6];
    const float* w2  = (const float*)d_in[7];
    const float* b2  = (const float*)d_in[8];
    const float* g1  = (const float*)d_in[9];
    const float* be1 = (const float*)d_in[10];
    const float* g2  = (const float*)d_in[11];
    const float* be2 = (const float*)d_in[12];
    float* out = (float*)d_out;

    const size_t M4 = (size_t)4 << 20;         // 4M elems
    _Float16* h  = (_Float16*)d_ws;            // [4096,1024] fp16, 8MB
    _Float16* Qb = h + M4;                     // 8MB
    _Float16* Kb = h + 2 * M4;                 // 8MB
    _Float16* Vb = h + 3 * M4;                 // 8MB
    float*    x1 = (float*)(h + 2 * M4);       // fp32 [4096,1024] = 16MB over dead K,V
    _Float16* f  = Qb;                         // FFN quarter [4096,1024] fp16, over dead attn-out

    dim3 blk(256);

    // 1. h = LN1(x)
    ln_kernel<<<4096, blk, 0, stream>>>(x, g1, be1, h);
    // 2. Q,K,V = h @ wq/wk/wv
    gemm_kernel<<<dim3(16, 64), blk, 0, stream>>>(h, wq, nullptr, nullptr, Qb, 1024, 1024, 1024, 0, 1);
    gemm_kernel<<<dim3(16, 64), blk, 0, stream>>>(h, wk, nullptr, nullptr, Kb, 1024, 1024, 1024, 0, 1);
    gemm_kernel<<<dim3(16, 64), blk, 0, stream>>>(h, wv, nullptr, nullptr, Vb, 1024, 1024, 1024, 0, 1);
    // 3. attention in-place over Q
    attn_kernel<<<dim3(32, 32), blk, 0, stream>>>(Qb, Kb, Vb, Qb);
    // 4. x1 = attnout @ wo + x   (fp32, K/V dead)
    gemm_kernel<<<dim3(16, 64), blk, 0, stream>>>(Qb, wo, nullptr, x, x1, 1024, 1024, 1024, 0, 0);
    // 5. h = LN2(x1)
    ln_kernel<<<4096, blk, 0, stream>>>(x1, g2, be2, h);
    // 6. FFN in 4 column-quarters: f_q = relu(h @ w1[:,q] + b1[q]);  x1 += f_q @ w2[q,:]
    for (int q = 0; q < 4; q++) {
        gemm_kernel<<<dim3(16, 64), blk, 0, stream>>>(h, w1 + q * 1024, b1 + q * 1024, nullptr, f,
                                                      1024, 1024, 4096, 1, 1);
        const float* bias2 = (q == 3) ? b2 : nullptr;
        void* outp = (q == 3) ? (void*)out : (void*)x1;
        gemm_kernel<<<dim3(16, 64), blk, 0, stream>>>(f, w2 + (size_t)q * 1024 * 1024, bias2, x1, outp,
                                                      1024, 1024, 1024, 0, 0);
    }
}

// Round 4
// 550.654 us; speedup vs baseline: 1.6882x; 1.6882x over previous
//
#include <hip/hip_runtime.h>

// EncoderBlock: x:[2,2048,1024] FP32 in/out. Internal fp16 MFMA (16x16x32_f16).
// B=2 S=2048 D=1024 H=16 DH=64 FF=4096, T=4096 tokens.
// ws (32MB, 4x8MB regions of 4M fp16 elems):
//   R0: h (LN out)        R1: Q -> attn-out -> f[0:4M]
//   R2: K -> f[4M:8M]     R3: V -> woT -> FFN weight scratch (w1Th | w2Th)
// d_out (16MB): wqT/wkT/wvT fp16 scratch early -> x1 fp32 -> final output.

typedef _Float16 half8 __attribute__((ext_vector_type(8)));
typedef _Float16 half4 __attribute__((ext_vector_type(4)));
typedef float floatx4 __attribute__((ext_vector_type(4)));

__device__ __forceinline__ void async16(const void* g, void* l) {
    __builtin_amdgcn_global_load_lds((const __attribute__((address_space(1))) unsigned int*)g,
                                     (__attribute__((address_space(3))) unsigned int*)l,
                                     16, 0, 0);
}

// ---------------- LayerNorm fp32 -> fp16 (ddof=1, g*(x-mean)/(std+eps)+b) ----
__global__ __launch_bounds__(256) void ln_kernel(const float* __restrict__ x,
                                                 const float* __restrict__ g,
                                                 const float* __restrict__ be,
                                                 _Float16* __restrict__ out) {
    int row = blockIdx.x;
    int tid = threadIdx.x;
    floatx4 v = ((const floatx4*)(x + (size_t)row * 1024))[tid];
    float s = 0.f, ss = 0.f;
#pragma unroll
    for (int i = 0; i < 4; i++) { s += v[i]; ss += v[i] * v[i]; }
#pragma unroll
    for (int off = 1; off < 64; off <<= 1) {
        s += __shfl_xor(s, off);
        ss += __shfl_xor(ss, off);
    }
    __shared__ float sm[8];
    int wave = tid >> 6, lane = tid & 63;
    if (lane == 0) { sm[wave] = s; sm[wave + 4] = ss; }
    __syncthreads();
    s = sm[0] + sm[1] + sm[2] + sm[3];
    ss = sm[4] + sm[5] + sm[6] + sm[7];
    float mean = s * (1.f / 1024.f);
    float var = (ss - s * mean) * (1.f / 1023.f);
    float rs = 1.f / (sqrtf(fmaxf(var, 0.f)) + 1e-6f);
    floatx4 gv = ((const floatx4*)g)[tid];
    floatx4 bv = ((const floatx4*)be)[tid];
    half4 o;
#pragma unroll
    for (int i = 0; i < 4; i++) o[i] = (_Float16)(gv[i] * (v[i] - mean) * rs + bv[i]);
    ((half4*)(out + (size_t)row * 1024))[tid] = o;
}

// ------- Transpose-convert: W[Kr][Nr] fp32 (row stride ldW) -> WT[Nr][Kr] fp16 -----
// grid (Nr/64, Kr/64), 256 threads.
__global__ __launch_bounds__(256) void convt_kernel(const float* __restrict__ W, int ldW,
                                                    _Float16* __restrict__ WT, int Kr) {
    __shared__ float t[64][65];
    int n0 = blockIdx.x * 64, k0 = blockIdx.y * 64;
    int tid = threadIdx.x;
    int r = tid >> 4, c4 = (tid & 15) * 4;
#pragma unroll
    for (int p = 0; p < 4; p++) {
        floatx4 v = *(const floatx4*)(W + (size_t)(k0 + r + p * 16) * ldW + n0 + c4);
#pragma unroll
        for (int j = 0; j < 4; j++) t[c4 + j][r + p * 16] = v[j];
    }
    __syncthreads();
#pragma unroll
    for (int p = 0; p < 4; p++) {
        int rr = r + p * 16;
        half4 o;
#pragma unroll
        for (int j = 0; j < 4; j++) o[j] = (_Float16)t[rr][c4 + j];
        *(half4*)(WT + (size_t)(n0 + rr) * Kr + k0 + c4) = o;
    }
}

// ---------------- MFMA GEMM (m97-style): C = [relu](A@BT^T + bias) + res -------
// A [M][K] fp16, BT [N][K] fp16 (pre-transposed weights), both staged via
// global_load_lds dwordx4 with XOR chunk-swizzle (conflict-free ds_read_b128).
// Tile 64Mx128N, BK=64, 4 waves at 32x64. res/C fp32 (may alias); C fp16 or fp32.
__global__ __launch_bounds__(256) void gemm_t(const _Float16* __restrict__ A,
                                              const _Float16* __restrict__ BT,
                                              const float* __restrict__ bias,
                                              const float* res, void* Cout,
                                              int N, int K, int relu_flag, int out_fp16) {
    __shared__ _Float16 As[64 * 64];    // [row][chunk^(row&7)][8] : 8KB
    __shared__ _Float16 Bs[128 * 64];   // 16KB
    int tid = threadIdx.x;
    int wave = tid >> 6, lane = tid & 63, quad = lane >> 4, l15 = lane & 15;
    int bm = blockIdx.y * 64, bn = blockIdx.x * 128;
    int wr = (wave & 1) * 32, wc = (wave >> 1) * 64;
    int lrow = lane >> 3, lch = lane & 7;

    floatx4 acc[2][4];
#pragma unroll
    for (int im = 0; im < 2; im++)
#pragma unroll
        for (int in = 0; in < 4; in++)
#pragma unroll
            for (int r = 0; r < 4; r++) acc[im][in][r] = 0.f;

    for (int k0 = 0; k0 < K; k0 += 64) {
        __syncthreads();   // previous iteration's LDS readers done
        // A tile 64x64: 8 groups of 8 rows; wave stages groups 2w..2w+1
#pragma unroll
        for (int ia = 0; ia < 2; ia++) {
            int gidx = 2 * wave + ia;
            int row = gidx * 8 + lrow;
            int ch = lch ^ (row & 7);
            async16(A + (size_t)(bm + row) * K + k0 + ch * 8, &As[gidx * 512]);
        }
        // B tile 128x64: 16 groups; wave stages 4w..4w+3
#pragma unroll
        for (int ib = 0; ib < 4; ib++) {
            int gidx = 4 * wave + ib;
            int row = gidx * 8 + lrow;
            int ch = lch ^ (row & 7);
            async16(BT + (size_t)(bn + row) * K + k0 + ch * 8, &Bs[gidx * 512]);
        }
        __syncthreads();   // drains vmcnt (global_load_lds) per barrier semantics

        half8 af[2][2], bf[4][2];
#pragma unroll
        for (int kk = 0; kk < 2; kk++) {
#pragma unroll
            for (int im = 0; im < 2; im++) {
                int m = wr + im * 16 + l15;
                af[im][kk] = *(const half8*)&As[m * 64 + ((((kk << 2) | quad) ^ (m & 7)) << 3)];
            }
#pragma unroll
            for (int in = 0; in < 4; in++) {
                int n = wc + in * 16 + l15;
                bf[in][kk] = *(const half8*)&Bs[n * 64 + ((((kk << 2) | quad) ^ (n & 7)) << 3)];
            }
        }
#pragma unroll
        for (int kk = 0; kk < 2; kk++)
#pragma unroll
            for (int im = 0; im < 2; im++)
#pragma unroll
                for (int in = 0; in < 4; in++)
                    acc[im][in] = __builtin_amdgcn_mfma_f32_16x16x32_f16(af[im][kk], bf[in][kk],
                                                                         acc[im][in], 0, 0, 0);
    }
    // epilogue: C/D layout col=lane&15, row=quad*4+reg
#pragma unroll
    for (int im = 0; im < 2; im++)
#pragma unroll
        for (int in = 0; in < 4; in++)
#pragma unroll
            for (int r = 0; r < 4; r++) {
                int row = bm + wr + im * 16 + quad * 4 + r;
                int col = bn + wc + in * 16 + l15;
                float val = acc[im][in][r];
                if (bias) val += bias[col];
                if (relu_flag) val = fmaxf(val, 0.f);
                if (res) val += res[(size_t)row * N + col];
                if (out_fp16) ((_Float16*)Cout)[(size_t)row * N + col] = (_Float16)val;
                else          ((float*)Cout)[(size_t)row * N + col] = val;
            }
}

// ---------------- Flash attention (unchanged from round 3) ----------------
__global__ __launch_bounds__(256) void attn_kernel(const _Float16* Q,
                                                   const _Float16* __restrict__ K,
                                                   const _Float16* __restrict__ V,
                                                   _Float16* O) {
    const int LD = 1024;
    int qt = blockIdx.x;
    int bh = blockIdx.y;
    int b = bh >> 4, h = bh & 15;
    int col0 = h * 64;
    int tbase = b * 2048;

    __shared__ _Float16 Qs[64][72];
    __shared__ _Float16 Ks[64][72];
    __shared__ _Float16 Vt[64][72];
    __shared__ _Float16 Ps[64][72];

    int tid = threadIdx.x;
    int wave = tid >> 6, lane = tid & 63, quad = lane >> 4, l15 = lane & 15;

#pragma unroll
    for (int i = 0; i < 2; i++) {
        int v = tid + i * 256;
        int r = v >> 3, c = (v & 7) * 8;
        *(half8*)&Qs[r][c] = *(const half8*)(Q + (size_t)(tbase + qt * 64 + r) * LD + col0 + c);
    }

    floatx4 zero = {0.f, 0.f, 0.f, 0.f};
    floatx4 o_acc[4];
#pragma unroll
    for (int jn = 0; jn < 4; jn++) o_acc[jn] = zero;
    float m_i[4] = {-1e30f, -1e30f, -1e30f, -1e30f};
    float l_i[4] = {0.f, 0.f, 0.f, 0.f};

    for (int kt = 0; kt < 32; kt++) {
        __syncthreads();
#pragma unroll
        for (int i = 0; i < 2; i++) {
            int v = tid + i * 256;
            int r = v >> 3, c = (v & 7) * 8;
            *(half8*)&Ks[r][c] = *(const half8*)(K + (size_t)(tbase + kt * 64 + r) * LD + col0 + c);
            half8 vv = *(const half8*)(V + (size_t)(tbase + kt * 64 + r) * LD + col0 + c);
#pragma unroll
            for (int j = 0; j < 8; j++) Vt[c + j][r] = vv[j];
        }
        __syncthreads();

        floatx4 s_acc[4];
#pragma unroll
        for (int jn = 0; jn < 4; jn++) s_acc[jn] = zero;
#pragma unroll
        for (int kk = 0; kk < 2; kk++) {
            half8 a = *(const half8*)&Qs[16 * wave + l15][kk * 32 + quad * 8];
#pragma unroll
            for (int jn = 0; jn < 4; jn++) {
                half8 bb = *(const half8*)&Ks[16 * jn + l15][kk * 32 + quad * 8];
                s_acc[jn] = __builtin_amdgcn_mfma_f32_16x16x32_f16(a, bb, s_acc[jn], 0, 0, 0);
            }
        }

        float alpha[4];
#pragma unroll
        for (int r = 0; r < 4; r++) {
            float mx = -1e30f;
#pragma unroll
            for (int jn = 0; jn < 4; jn++) {
                s_acc[jn][r] *= 0.125f;
                mx = fmaxf(mx, s_acc[jn][r]);
            }
#pragma unroll
            for (int off = 1; off < 16; off <<= 1) mx = fmaxf(mx, __shfl_xor(mx, off));
            float mnew = fmaxf(m_i[r], mx);
            float d = m_i[r] - mnew;
            alpha[r] = (d < -60.f) ? 0.f : __expf(d);
            m_i[r] = mnew;
        }
#pragma unroll
        for (int r = 0; r < 4; r++) {
            float sum = 0.f;
#pragma unroll
            for (int jn = 0; jn < 4; jn++) {
                float d = s_acc[jn][r] - m_i[r];
                float p = (d < -60.f) ? 0.f : __expf(d);
                s_acc[jn][r] = p;
                sum += p;
            }
#pragma unroll
            for (int off = 1; off < 16; off <<= 1) sum += __shfl_xor(sum, off);
            l_i[r] = l_i[r] * alpha[r] + sum;
        }

#pragma unroll
        for (int jn = 0; jn < 4; jn++)
#pragma unroll
            for (int r = 0; r < 4; r++)
                Ps[16 * wave + quad * 4 + r][16 * jn + l15] = (_Float16)s_acc[jn][r];
        __syncthreads();

#pragma unroll
        for (int jn = 0; jn < 4; jn++)
#pragma unroll
            for (int r = 0; r < 4; r++) o_acc[jn][r] *= alpha[r];
#pragma unroll
        for (int kk = 0; kk < 2; kk++) {
            half8 a = *(const half8*)&Ps[16 * wave + l15][kk * 32 + quad * 8];
#pragma unroll
            for (int jn = 0; jn < 4; jn++) {
                half8 bb = *(const half8*)&Vt[16 * jn + l15][kk * 32 + quad * 8];
                o_acc[jn] = __builtin_amdgcn_mfma_f32_16x16x32_f16(a, bb, o_acc[jn], 0, 0, 0);
            }
        }
    }

#pragma unroll
    for (int jn = 0; jn < 4; jn++)
#pragma unroll
        for (int r = 0; r < 4; r++) {
            float val = o_acc[jn][r] / l_i[r];
            int row = tbase + qt * 64 + 16 * wave + quad * 4 + r;
            O[(size_t)row * LD + col0 + 16 * jn + l15] = (_Float16)val;
        }
}

extern "C" void kernel_launch(void* const* d_in, const int* in_sizes, int n_in,
                              void* d_out, int out_size, void* d_ws, size_t ws_size,
                              hipStream_t stream) {
    const float* x   = (const float*)d_in[0];
    const float* wq  = (const float*)d_in[1];
    const float* wk  = (const float*)d_in[2];
    const float* wv  = (const float*)d_in[3];
    const float* wo  = (const float*)d_in[4];
    const float* w1  = (const float*)d_in[5];
    const float* b1  = (const float*)d_in[6];
    const float* w2  = (const float*)d_in[7];
    const float* b2  = (const float*)d_in[8];
    const float* g1  = (const float*)d_in[9];
    const float* be1 = (const float*)d_in[10];
    const float* g2  = (const float*)d_in[11];
    const float* be2 = (const float*)d_in[12];

    const size_t M1 = (size_t)1 << 20;
    _Float16* R0 = (_Float16*)d_ws;        // h
    _Float16* R1 = R0 + 4 * M1;            // Q / attn-out / f (spans R1+R2)
    _Float16* R2 = R0 + 8 * M1;            // K
    _Float16* R3 = R0 + 12 * M1;           // V / woT / FFN weight scratch

    _Float16* wqT = (_Float16*)d_out;      // d_out as early fp16 scratch (dead until O-proj)
    _Float16* wkT = wqT + 1 * M1;
    _Float16* wvT = wqT + 2 * M1;
    float* x1 = (float*)d_out;             // O-proj output overwrites scratch
    float* out = (float*)d_out;

    dim3 blk(256);

    // weight converts for QKV into d_out scratch
    convt_kernel<<<dim3(16, 16), blk, 0, stream>>>(wq, 1024, wqT, 1024);
    convt_kernel<<<dim3(16, 16), blk, 0, stream>>>(wk, 1024, wkT, 1024);
    convt_kernel<<<dim3(16, 16), blk, 0, stream>>>(wv, 1024, wvT, 1024);
    // h = LN1(x)
    ln_kernel<<<4096, blk, 0, stream>>>(x, g1, be1, R0);
    // Q,K,V
    gemm_t<<<dim3(8, 64), blk, 0, stream>>>(R0, wqT, nullptr, nullptr, R1, 1024, 1024, 0, 1);
    gemm_t<<<dim3(8, 64), blk, 0, stream>>>(R0, wkT, nullptr, nullptr, R2, 1024, 1024, 0, 1);
    gemm_t<<<dim3(8, 64), blk, 0, stream>>>(R0, wvT, nullptr, nullptr, R3, 1024, 1024, 0, 1);
    // attention in-place over Q
    attn_kernel<<<dim3(32, 32), blk, 0, stream>>>(R1, R2, R3, R1);
    // woT into R3 (V dead), then x1 = attn@wo + x -> d_out (fp32)
    convt_kernel<<<dim3(16, 16), blk, 0, stream>>>(wo, 1024, R3, 1024);
    gemm_t<<<dim3(8, 64), blk, 0, stream>>>(R1, R3, nullptr, x, x1, 1024, 1024, 0, 0);
    // h = LN2(x1)
    ln_kernel<<<4096, blk, 0, stream>>>(x1, g2, be2, R0);
    // FFN in two 2048-wide halves; f = [4096,2048] fp16 over R1+R2
    for (int hh = 0; hh < 2; hh++) {
        _Float16* w1Th = R3;                    // [2048][1024] = 4MB
        _Float16* w2Th = R3 + 2 * M1;           // [1024][2048] = 4MB
        convt_kernel<<<dim3(32, 16), blk, 0, stream>>>(w1 + hh * 2048, 4096, w1Th, 1024);
        gemm_t<<<dim3(16, 64), blk, 0, stream>>>(R0, w1Th, b1 + hh * 2048, nullptr, R1,
                                                 2048, 1024, 1, 1);
        convt_kernel<<<dim3(16, 32), blk, 0, stream>>>(w2 + (size_t)hh * 2048 * 1024, 1024, w2Th, 2048);
        gemm_t<<<dim3(8, 64), blk, 0, stream>>>(R1, w2Th, (hh == 1) ? b2 : nullptr, x1, out,
                                                1024, 2048, 0, 0);
    }
}

// Round 5
// 461.102 us; speedup vs baseline: 2.0161x; 1.1942x over previous
//
#include <hip/hip_runtime.h>

// EncoderBlock: x:[2,2048,1024] FP32 in/out. Internal fp16 MFMA.
// B=2 S=2048 D=1024 H=16 DH=64 FF=4096, T=4096 tokens.
// ws (32MB, 4x8MB regions of 4M fp16 elems):
//   R0: h (LN1 out) -> Vt[32][64][2048] -> h (LN2 out)
//   R1: Q -> attn-out -> f[0:4M]
//   R2: K -> f[4M:8M]
//   R3: V -> woT -> FFN weight scratch (w1Th | w2Th)
// d_out (16MB): wqT/wkT/wvT fp16 scratch early -> x1 fp32 -> final output.

typedef _Float16 half8 __attribute__((ext_vector_type(8)));
typedef _Float16 half4 __attribute__((ext_vector_type(4)));
typedef float floatx4 __attribute__((ext_vector_type(4)));

__device__ __forceinline__ void async16(const void* g, void* l) {
    __builtin_amdgcn_global_load_lds((const __attribute__((address_space(1))) unsigned int*)g,
                                     (__attribute__((address_space(3))) unsigned int*)l,
                                     16, 0, 0);
}

// ---------------- LayerNorm fp32 -> fp16 (ddof=1, g*(x-mean)/(std+eps)+b) ----
__global__ __launch_bounds__(256) void ln_kernel(const float* __restrict__ x,
                                                 const float* __restrict__ g,
                                                 const float* __restrict__ be,
                                                 _Float16* __restrict__ out) {
    int row = blockIdx.x;
    int tid = threadIdx.x;
    floatx4 v = ((const floatx4*)(x + (size_t)row * 1024))[tid];
    float s = 0.f, ss = 0.f;
#pragma unroll
    for (int i = 0; i < 4; i++) { s += v[i]; ss += v[i] * v[i]; }
#pragma unroll
    for (int off = 1; off < 64; off <<= 1) {
        s += __shfl_xor(s, off);
        ss += __shfl_xor(ss, off);
    }
    __shared__ float sm[8];
    int wave = tid >> 6, lane = tid & 63;
    if (lane == 0) { sm[wave] = s; sm[wave + 4] = ss; }
    __syncthreads();
    s = sm[0] + sm[1] + sm[2] + sm[3];
    ss = sm[4] + sm[5] + sm[6] + sm[7];
    float mean = s * (1.f / 1024.f);
    float var = (ss - s * mean) * (1.f / 1023.f);
    float rs = 1.f / (sqrtf(fmaxf(var, 0.f)) + 1e-6f);
    floatx4 gv = ((const floatx4*)g)[tid];
    floatx4 bv = ((const floatx4*)be)[tid];
    half4 o;
#pragma unroll
    for (int i = 0; i < 4; i++) o[i] = (_Float16)(gv[i] * (v[i] - mean) * rs + bv[i]);
    ((half4*)(out + (size_t)row * 1024))[tid] = o;
}

// ------- Transpose-convert: W[Kr][Nr] fp32 (row stride ldW) -> WT[Nr][Kr] fp16 -----
__global__ __launch_bounds__(256) void convt_kernel(const float* __restrict__ W, int ldW,
                                                    _Float16* __restrict__ WT, int Kr) {
    __shared__ float t[64][65];
    int n0 = blockIdx.x * 64, k0 = blockIdx.y * 64;
    int tid = threadIdx.x;
    int r = tid >> 4, c4 = (tid & 15) * 4;
#pragma unroll
    for (int p = 0; p < 4; p++) {
        floatx4 v = *(const floatx4*)(W + (size_t)(k0 + r + p * 16) * ldW + n0 + c4);
#pragma unroll
        for (int j = 0; j < 4; j++) t[c4 + j][r + p * 16] = v[j];
    }
    __syncthreads();
#pragma unroll
    for (int p = 0; p < 4; p++) {
        int rr = r + p * 16;
        half4 o;
#pragma unroll
        for (int j = 0; j < 4; j++) o[j] = (_Float16)t[rr][c4 + j];
        *(half4*)(WT + (size_t)(n0 + rr) * Kr + k0 + c4) = o;
    }
}

// ------- V transpose fp16: V[4096][1024] -> Vt[bh=32][dh=64][s=2048] ----------
// grid (64 token-tiles, 16 d-tiles). d-tile == one head's dh block.
__global__ __launch_bounds__(256) void transv_kernel(const _Float16* __restrict__ V,
                                                     _Float16* __restrict__ Vt) {
    __shared__ _Float16 t[64][72];
    int t0 = blockIdx.x * 64, d0 = blockIdx.y * 64;
    int tid = threadIdx.x;
#pragma unroll
    for (int i = 0; i < 2; i++) {
        int v = tid + i * 256;
        int r = v >> 3, c = (v & 7) * 8;
        half8 vv = *(const half8*)(V + (size_t)(t0 + r) * 1024 + d0 + c);
#pragma unroll
        for (int j = 0; j < 8; j++) t[c + j][r] = vv[j];
    }
    __syncthreads();
    int bh = (t0 >> 11) * 16 + (d0 >> 6);
    int sbase = t0 & 2047;
#pragma unroll
    for (int i = 0; i < 2; i++) {
        int v = tid + i * 256;
        int r = v >> 3, c = (v & 7) * 8;   // r = dh, c = s-chunk
        half8 o = *(const half8*)&t[r][c];
        *(half8*)(Vt + ((size_t)bh * 64 + r) * 2048 + sbase + c) = o;
    }
}

// ---------------- MFMA GEMM (m97-style): C = [relu](A@BT^T + bias) + res -------
__global__ __launch_bounds__(256) void gemm_t(const _Float16* __restrict__ A,
                                              const _Float16* __restrict__ BT,
                                              const float* __restrict__ bias,
                                              const float* res, void* Cout,
                                              int N, int K, int relu_flag, int out_fp16) {
    __shared__ _Float16 As[64 * 64];
    __shared__ _Float16 Bs[128 * 64];
    int tid = threadIdx.x;
    int wave = tid >> 6, lane = tid & 63, quad = lane >> 4, l15 = lane & 15;
    int bm = blockIdx.y * 64, bn = blockIdx.x * 128;
    int wr = (wave & 1) * 32, wc = (wave >> 1) * 64;
    int lrow = lane >> 3, lch = lane & 7;

    floatx4 acc[2][4];
#pragma unroll
    for (int im = 0; im < 2; im++)
#pragma unroll
        for (int in = 0; in < 4; in++)
#pragma unroll
            for (int r = 0; r < 4; r++) acc[im][in][r] = 0.f;

    for (int k0 = 0; k0 < K; k0 += 64) {
        __syncthreads();
#pragma unroll
        for (int ia = 0; ia < 2; ia++) {
            int gidx = 2 * wave + ia;
            int row = gidx * 8 + lrow;
            int ch = lch ^ (row & 7);
            async16(A + (size_t)(bm + row) * K + k0 + ch * 8, &As[gidx * 512]);
        }
#pragma unroll
        for (int ib = 0; ib < 4; ib++) {
            int gidx = 4 * wave + ib;
            int row = gidx * 8 + lrow;
            int ch = lch ^ (row & 7);
            async16(BT + (size_t)(bn + row) * K + k0 + ch * 8, &Bs[gidx * 512]);
        }
        __syncthreads();

        half8 af[2][2], bf[4][2];
#pragma unroll
        for (int kk = 0; kk < 2; kk++) {
#pragma unroll
            for (int im = 0; im < 2; im++) {
                int m = wr + im * 16 + l15;
                af[im][kk] = *(const half8*)&As[m * 64 + ((((kk << 2) | quad) ^ (m & 7)) << 3)];
            }
#pragma unroll
            for (int in = 0; in < 4; in++) {
                int n = wc + in * 16 + l15;
                bf[in][kk] = *(const half8*)&Bs[n * 64 + ((((kk << 2) | quad) ^ (n & 7)) << 3)];
            }
        }
#pragma unroll
        for (int kk = 0; kk < 2; kk++)
#pragma unroll
            for (int im = 0; im < 2; im++)
#pragma unroll
                for (int in = 0; in < 4; in++)
                    acc[im][in] = __builtin_amdgcn_mfma_f32_16x16x32_f16(af[im][kk], bf[in][kk],
                                                                         acc[im][in], 0, 0, 0);
    }
#pragma unroll
    for (int im = 0; im < 2; im++)
#pragma unroll
        for (int in = 0; in < 4; in++)
#pragma unroll
            for (int r = 0; r < 4; r++) {
                int row = bm + wr + im * 16 + quad * 4 + r;
                int col = bn + wc + in * 16 + l15;
                float val = acc[im][in][r];
                if (bias) val += bias[col];
                if (relu_flag) val = fmaxf(val, 0.f);
                if (res) val += res[(size_t)row * N + col];
                if (out_fp16) ((_Float16*)Cout)[(size_t)row * N + col] = (_Float16)val;
                else          ((float*)Cout)[(size_t)row * N + col] = val;
            }
}

// ---------------- Flash attention v2: S^T trick, no P round-trip ----------------
// Q,K: [token][1024] fp16 (head slice col0). Vt: [bh][dh=64][s=2048] fp16.
// O over Q in-place: block (qt,bh) only touches its own Q tile, staged before writes.
// Per wave: 16 q-rows (q = 16*wave + l15). m/l are per-lane scalars.
__global__ __launch_bounds__(256) void attn_kernel(const _Float16* Q,
                                                   const _Float16* __restrict__ K,
                                                   const _Float16* __restrict__ Vt,
                                                   _Float16* O) {
    __shared__ _Float16 Qs[64 * 64];
    __shared__ _Float16 Ks[64 * 64];
    __shared__ _Float16 Vs[64 * 64];
    int qt = blockIdx.x, bh = blockIdx.y;
    int b = bh >> 4, h = bh & 15;
    int col0 = h * 64, tbase = b * 2048;
    int tid = threadIdx.x;
    int wave = tid >> 6, lane = tid & 63, quad = lane >> 4, l15 = lane & 15;
    int lrow = lane >> 3, lch = lane & 7;

    // stage Q tile once (swizzled async16)
#pragma unroll
    for (int i = 0; i < 2; i++) {
        int g = 2 * wave + i;
        int row = g * 8 + lrow;
        int ch = lch ^ (row & 7);
        async16(Q + (size_t)(tbase + qt * 64 + row) * 1024 + col0 + ch * 8, &Qs[g * 512]);
    }

    floatx4 o_acc[4];
#pragma unroll
    for (int im = 0; im < 4; im++)
#pragma unroll
        for (int r = 0; r < 4; r++) o_acc[im][r] = 0.f;
    float m_i = -1e30f, l_i = 0.f;

    for (int kt = 0; kt < 32; kt++) {
        __syncthreads();   // previous iteration's Ks/Vs readers done
#pragma unroll
        for (int i = 0; i < 2; i++) {
            int g = 2 * wave + i;
            int row = g * 8 + lrow;
            int ch = lch ^ (row & 7);
            async16(K + (size_t)(tbase + kt * 64 + row) * 1024 + col0 + ch * 8, &Ks[g * 512]);
            async16(Vt + ((size_t)bh * 64 + row) * 2048 + kt * 64 + ch * 8, &Vs[g * 512]);
        }
        __syncthreads();   // drains async loads (also covers Q on kt==0)

        // S^T tiles: D[kidx = 16jn+quad*4+r][q = l15], a=K rows, b=Q rows
        int rowq = 16 * wave + l15;
        half8 bq[2];
#pragma unroll
        for (int kk = 0; kk < 2; kk++)
            bq[kk] = *(const half8*)&Qs[rowq * 64 + ((((kk << 2) | quad) ^ (rowq & 7)) << 3)];
        floatx4 s_acc[4];
#pragma unroll
        for (int jn = 0; jn < 4; jn++)
#pragma unroll
            for (int r = 0; r < 4; r++) s_acc[jn][r] = 0.f;
#pragma unroll
        for (int jn = 0; jn < 4; jn++) {
            int rowk = 16 * jn + l15;
#pragma unroll
            for (int kk = 0; kk < 2; kk++) {
                half8 ak = *(const half8*)&Ks[rowk * 64 + ((((kk << 2) | quad) ^ (rowk & 7)) << 3)];
                s_acc[jn] = __builtin_amdgcn_mfma_f32_16x16x32_f16(ak, bq[kk], s_acc[jn], 0, 0, 0);
            }
        }

        // online softmax: all 16 values in-lane are the SAME q-row (l15);
        // keys spread over regs/tiles (16) and quads -> 2 shuffle steps
        float mx = -1e30f;
#pragma unroll
        for (int jn = 0; jn < 4; jn++)
#pragma unroll
            for (int r = 0; r < 4; r++) {
                s_acc[jn][r] *= 0.125f;   // 1/sqrt(64)
                mx = fmaxf(mx, s_acc[jn][r]);
            }
        mx = fmaxf(mx, __shfl_xor(mx, 16));
        mx = fmaxf(mx, __shfl_xor(mx, 32));
        float mnew = fmaxf(m_i, mx);
        float dd = m_i - mnew;
        float alpha = (dd < -60.f) ? 0.f : __expf(dd);
        m_i = mnew;

        float sum = 0.f;
#pragma unroll
        for (int jn = 0; jn < 4; jn++)
#pragma unroll
            for (int r = 0; r < 4; r++) {
                float d2 = s_acc[jn][r] - mnew;
                float p = (d2 < -60.f) ? 0.f : __expf(d2);
                s_acc[jn][r] = p;
                sum += p;
            }
        sum += __shfl_xor(sum, 16);
        sum += __shfl_xor(sum, 32);
        l_i = l_i * alpha + sum;

        // P^T C-layout regs ARE the B-fragments of mfma_16x16x16 (k=quad*4+j)
        half4 pb[4];
#pragma unroll
        for (int jn = 0; jn < 4; jn++)
#pragma unroll
            for (int r = 0; r < 4; r++) pb[jn][r] = (_Float16)s_acc[jn][r];

        // O^T[dh][q] accumulate: a = Vt rows (lane dh = l15), b = P^T
#pragma unroll
        for (int im = 0; im < 4; im++)
#pragma unroll
            for (int r = 0; r < 4; r++) o_acc[im][r] *= alpha;
#pragma unroll
        for (int im = 0; im < 4; im++) {
            int rowv = 16 * im + l15;
#pragma unroll
            for (int ks = 0; ks < 4; ks++) {
                int off = rowv * 128 + ((((2 * ks) | (quad >> 1)) ^ (rowv & 7)) << 4) + (quad & 1) * 8;
                half4 av = *(const half4*)((const char*)Vs + off);
                o_acc[im] = __builtin_amdgcn_mfma_f32_16x16x16f16(av, pb[ks], o_acc[im], 0, 0, 0);
            }
        }
    }

    // epilogue: O^T tile im: lane holds dh = 16im+quad*4+r (4 consecutive), q = l15
    float rl = 1.f / l_i;
#pragma unroll
    for (int im = 0; im < 4; im++) {
        half4 o;
#pragma unroll
        for (int r = 0; r < 4; r++) o[r] = (_Float16)(o_acc[im][r] * rl);
        *(half4*)&O[(size_t)(tbase + qt * 64 + wave * 16 + l15) * 1024 + col0 + im * 16 + quad * 4] = o;
    }
}

extern "C" void kernel_launch(void* const* d_in, const int* in_sizes, int n_in,
                              void* d_out, int out_size, void* d_ws, size_t ws_size,
                              hipStream_t stream) {
    const float* x   = (const float*)d_in[0];
    const float* wq  = (const float*)d_in[1];
    const float* wk  = (const float*)d_in[2];
    const float* wv  = (const float*)d_in[3];
    const float* wo  = (const float*)d_in[4];
    const float* w1  = (const float*)d_in[5];
    const float* b1  = (const float*)d_in[6];
    const float* w2  = (const float*)d_in[7];
    const float* b2  = (const float*)d_in[8];
    const float* g1  = (const float*)d_in[9];
    const float* be1 = (const float*)d_in[10];
    const float* g2  = (const float*)d_in[11];
    const float* be2 = (const float*)d_in[12];

    const size_t M1 = (size_t)1 << 20;
    _Float16* R0 = (_Float16*)d_ws;        // h -> Vt -> h
    _Float16* R1 = R0 + 4 * M1;            // Q / attn-out / f[0:4M]
    _Float16* R2 = R0 + 8 * M1;            // K / f[4M:8M]
    _Float16* R3 = R0 + 12 * M1;           // V / woT / FFN weight scratch

    _Float16* wqT = (_Float16*)d_out;      // d_out fp16 scratch (dead until O-proj)
    _Float16* wkT = wqT + 1 * M1;
    _Float16* wvT = wqT + 2 * M1;
    float* x1 = (float*)d_out;
    float* out = (float*)d_out;

    dim3 blk(256);

    convt_kernel<<<dim3(16, 16), blk, 0, stream>>>(wq, 1024, wqT, 1024);
    convt_kernel<<<dim3(16, 16), blk, 0, stream>>>(wk, 1024, wkT, 1024);
    convt_kernel<<<dim3(16, 16), blk, 0, stream>>>(wv, 1024, wvT, 1024);
    ln_kernel<<<4096, blk, 0, stream>>>(x, g1, be1, R0);
    gemm_t<<<dim3(8, 64), blk, 0, stream>>>(R0, wqT, nullptr, nullptr, R1, 1024, 1024, 0, 1);
    gemm_t<<<dim3(8, 64), blk, 0, stream>>>(R0, wkT, nullptr, nullptr, R2, 1024, 1024, 0, 1);
    gemm_t<<<dim3(8, 64), blk, 0, stream>>>(R0, wvT, nullptr, nullptr, R3, 1024, 1024, 0, 1);
    // V -> Vt (R0; h dead after QKV)
    transv_kernel<<<dim3(64, 16), blk, 0, stream>>>(R3, R0);
    // attention in-place over Q
    attn_kernel<<<dim3(32, 32), blk, 0, stream>>>(R1, R2, R0, R1);
    // woT into R3 (V dead), then x1 = attn@wo + x
    convt_kernel<<<dim3(16, 16), blk, 0, stream>>>(wo, 1024, R3, 1024);
    gemm_t<<<dim3(8, 64), blk, 0, stream>>>(R1, R3, nullptr, x, x1, 1024, 1024, 0, 0);
    // LN2 (Vt dead)
    ln_kernel<<<4096, blk, 0, stream>>>(x1, g2, be2, R0);
    // FFN in two 2048-wide halves; f spans R1+R2
    for (int hh = 0; hh < 2; hh++) {
        _Float16* w1Th = R3;
        _Float16* w2Th = R3 + 2 * M1;
        convt_kernel<<<dim3(32, 16), blk, 0, stream>>>(w1 + hh * 2048, 4096, w1Th, 1024);
        gemm_t<<<dim3(16, 64), blk, 0, stream>>>(R0, w1Th, b1 + hh * 2048, nullptr, R1,
                                                 2048, 1024, 1, 1);
        convt_kernel<<<dim3(16, 32), blk, 0, stream>>>(w2 + (size_t)hh * 2048 * 1024, 1024, w2Th, 2048);
        gemm_t<<<dim3(8, 64), blk, 0, stream>>>(R1, w2Th, (hh == 1) ? b2 : nullptr, x1, out,
                                                1024, 2048, 0, 0);
    }
}